// Round 19
// baseline (425.624 us; speedup 1.0000x reference)
//
#include <hip/hip_runtime.h>

#define SC2   0.18033688011112042f   // 0.125 * log2(e)
#define PSTR  36

typedef __attribute__((ext_vector_type(8)))  __bf16       bf16x8;
typedef __attribute__((ext_vector_type(16))) float        f32x16;
typedef __attribute__((ext_vector_type(4)))  float        f32x4;
typedef __attribute__((ext_vector_type(4)))  unsigned int u32x4;
typedef __attribute__((ext_vector_type(2)))  unsigned int u32x2;

#define ROWPAT(g, hi) ((((g)&3)) + 8*((g)>>2) + 4*(hi))

__device__ inline unsigned short f2bf(float f){
  unsigned u = __builtin_bit_cast(unsigned, f);
  u += 0x7FFFu + ((u >> 16) & 1u);
  return (unsigned short)(u >> 16);
}
__device__ inline float bf2f(unsigned short h){
  unsigned u = ((unsigned)h) << 16;
  return __builtin_bit_cast(float, u);
}
__device__ inline unsigned pack2bf(float lo, float hi){
  return (unsigned)f2bf(lo) | ((unsigned)f2bf(hi) << 16);
}
__device__ inline f32x16 zero16(){
  f32x16 z;
  #pragma unroll
  for (int i=0;i<16;i++) z[i]=0.f;
  return z;
}

// ---------------- K0: 4x W (512x512 fp32, [k][n]) -> Wt bf16 [n][k]; grid.z selects ----------------
__global__ __launch_bounds__(256) void transpose_w4_kernel(
    const float* __restrict__ Wq, const float* __restrict__ Wk,
    const float* __restrict__ Wv, const float* __restrict__ Wf,
    unsigned short* __restrict__ Tq, unsigned short* __restrict__ Tk,
    unsigned short* __restrict__ Tv, unsigned short* __restrict__ Tf){
  const int z = blockIdx.z;
  const float* W = z==0 ? Wq : (z==1 ? Wk : (z==2 ? Wv : Wf));
  unsigned short* Wt = z==0 ? Tq : (z==1 ? Tk : (z==2 ? Tv : Tf));
  __shared__ unsigned short t[32][33];
  const int n0 = blockIdx.x*32, k0 = blockIdx.y*32;
  const int tx = threadIdx.x & 31, ty = threadIdx.x >> 5;
  #pragma unroll
  for (int i=0;i<4;i++){
    int k = ty*4 + i;
    t[k][tx] = f2bf(W[(size_t)(k0+k)*512 + n0+tx]);
  }
  __syncthreads();
  #pragma unroll
  for (int i=0;i<4;i++){
    int n = ty*4+i;
    Wt[(size_t)(n0+n)*512 + k0 + tx] = t[tx][n];
  }
}

// ---------------- K0c: Ebf[u][d] = bf16(E[2047-u][d]) ----------------
__global__ __launch_bounds__(256) void erev_kernel(const float* __restrict__ E,
                                                   unsigned short* __restrict__ Ebf){
  const int i = blockIdx.x*256 + threadIdx.x;
  const int base = i*4;
  const int u = base >> 6, d = base & 63;
  f32x4 v = *(const f32x4*)(E + (size_t)(2047 - u)*64 + d);
  unsigned short o[4];
  #pragma unroll
  for (int j=0;j<4;j++) o[j] = f2bf(v[j]);
  *(u32x2*)(Ebf + (size_t)u*64 + d) = u32x2{(unsigned)o[0] | ((unsigned)o[1]<<16),
                                            (unsigned)o[2] | ((unsigned)o[3]<<16)};
}

// ---------------- K1: fused QKV projections; V (z==2) written chunk-blocked directly ----------------
__global__ __launch_bounds__(256,2) void proj3_gemm_kernel(
    const float* __restrict__ X0, const float* __restrict__ X1, const float* __restrict__ X2,
    const unsigned int* __restrict__ W0, const unsigned int* __restrict__ W1, const unsigned int* __restrict__ W2,
    const float* __restrict__ b0, const float* __restrict__ b1, const float* __restrict__ b2,
    unsigned short* __restrict__ Y0, unsigned short* __restrict__ Y1, unsigned short* __restrict__ Y2)
{
  const int z = blockIdx.z;
  const float* X = z==0 ? X0 : (z==1 ? X1 : X2);
  const unsigned int* Wt = z==0 ? W0 : (z==1 ? W1 : W2);
  const float* bias = z==0 ? b0 : (z==1 ? b1 : b2);
  unsigned short* Y = z==0 ? Y0 : (z==1 ? Y1 : Y2);

  __shared__ unsigned int Al[128][17];
  __shared__ unsigned int Bl[128][17];
  const int n0 = blockIdx.x * 128;
  const int m0 = blockIdx.y * 128;
  const int tid = threadIdx.x;
  const int lane = tid & 63, wave = tid >> 6;
  const int lr = lane & 31, hi = lane >> 5;
  const int wr = wave >> 1, wc = wave & 1;
  const int r = tid & 127, kh = tid >> 7;

  f32x16 acc[2][2];
  acc[0][0]=zero16(); acc[0][1]=zero16(); acc[1][0]=zero16(); acc[1][1]=zero16();

  for (int k0=0; k0<512; k0+=32){
    const float* Xr = X + (size_t)(m0 + r)*512 + k0 + kh*16;
    #pragma unroll
    for (int c=0;c<2;c++){
      f32x4 x0 = *(const f32x4*)(Xr + c*8);
      f32x4 x1 = *(const f32x4*)(Xr + c*8 + 4);
      Al[r][kh*8 + c*4 + 0] = pack2bf(x0[0], x0[1]);
      Al[r][kh*8 + c*4 + 1] = pack2bf(x0[2], x0[3]);
      Al[r][kh*8 + c*4 + 2] = pack2bf(x1[0], x1[1]);
      Al[r][kh*8 + c*4 + 3] = pack2bf(x1[2], x1[3]);
    }
    const unsigned int* Wr = Wt + (size_t)(n0 + r)*256 + (k0>>1) + kh*8;
    #pragma unroll
    for (int c=0;c<8;c++) Bl[r][kh*8 + c] = Wr[c];
    __syncthreads();
    #pragma unroll
    for (int t=0;t<2;t++){
      bf16x8 af[2], bfr[2];
      #pragma unroll
      for (int mt=0;mt<2;mt++){
        u32x4 w;
        #pragma unroll
        for (int j=0;j<4;j++) w[j] = Al[wr*64 + mt*32 + lr][t*8 + hi*4 + j];
        af[mt] = __builtin_bit_cast(bf16x8, w);
      }
      #pragma unroll
      for (int nt=0;nt<2;nt++){
        u32x4 w;
        #pragma unroll
        for (int j=0;j<4;j++) w[j] = Bl[wc*64 + nt*32 + lr][t*8 + hi*4 + j];
        bfr[nt] = __builtin_bit_cast(bf16x8, w);
      }
      #pragma unroll
      for (int mt=0;mt<2;mt++)
        #pragma unroll
        for (int nt=0;nt<2;nt++)
          acc[mt][nt] = __builtin_amdgcn_mfma_f32_32x32x16_bf16(af[mt], bfr[nt], acc[mt][nt], 0,0,0);
    }
    __syncthreads();
  }

  #pragma unroll
  for (int mt=0;mt<2;mt++)
    #pragma unroll
    for (int nt=0;nt<2;nt++){
      const int n = n0 + wc*64 + nt*32 + lr;
      const float bv = bias[n];
      const int h = n >> 6, dh = n & 63;
      #pragma unroll
      for (int g=0; g<16; g++){
        const int m = m0 + wr*64 + mt*32 + ROWPAT(g,hi);
        const int b = m >> 11, l = m & 2047;
        const unsigned short val = f2bf(acc[mt][nt][g] + bv);
        if (z == 2){
          // chunk-blocked V: [bh][l>>5][dh][l&31]
          Y[(size_t)(b*8 + h)*131072 + (size_t)(l >> 5)*2048 + (size_t)dh*32 + (l & 31)] = val;
        } else {
          Y[((size_t)(b*8 + h)*2048 + l)*64 + dh] = val;
        }
      }
    }
}

// ---- task mapping shared by K2a/K2b: bid in [0,8192); quarter s-ranges ----
#define ATTN_TASK_MAP()                                   \
  const int bid = blockIdx.x;                             \
  const int xcd = bid & 7;                                \
  const int j   = bid >> 3;      /* 0..1023 */            \
  const int bhg = xcd*4 + (j >> 8);                       \
  const int jj  = j & 255;                                \
  const int quarter = jj & 3;                             \
  const int ltile = 63 - (jj >> 2);                       \
  const int l0w = ltile*32;                               \
  const int c_max = ltile;                                \
  const int clo = quarter*16, chi = clo + 15;             \
  const int relhi = c_max < chi ? c_max : chi;            \
  const int nr_lo = (c_max+1 > clo) ? c_max+1 : clo;

// ---------------- K2a: denominator pass (8192 x 64 thr, zero barriers) ----------------
__global__ __launch_bounds__(64) void attn_d_kernel(
    const unsigned short* __restrict__ Q,
    const unsigned short* __restrict__ Kb,
    const unsigned short* __restrict__ Ebf,
    float* __restrict__ dws)
{
  __shared__ unsigned short slab[2*32*PSTR];   // Wa | Wb
  const int tid = threadIdx.x;
  const int lane = tid & 63;
  const int lr = lane & 31;
  const int hi = lane >> 5;
  ATTN_TASK_MAP();

  unsigned short* Wa = slab;
  unsigned short* Wb = Wa + 32*PSTR;

  const unsigned short* Qrow = Q + ((size_t)bhg*2048 + l0w + lr)*64;
  bf16x8 qf[4];
  #pragma unroll
  for (int t=0;t<4;t++) qf[t] = *(const bf16x8*)(Qrow + t*16 + hi*8);
  const unsigned short* Krows = Kb + (size_t)bhg*2048*64;

  float dpart[16];
  #pragma unroll
  for (int g=0;g<16;g++) dpart[g] = 0.f;

  #pragma unroll 2
  for (int c = nr_lo; c <= chi; ++c){          // no-rel chunks
    const int s0 = c*32;
    f32x16 acc = zero16();
    const unsigned short* Krow = Krows + (size_t)(s0 + lr)*64;
    __builtin_amdgcn_s_setprio(1);
    #pragma unroll
    for (int t=0;t<4;t++){
      bf16x8 kf = *(const bf16x8*)(Krow + t*16 + hi*8);
      acc = __builtin_amdgcn_mfma_f32_32x32x16_bf16(qf[t], kf, acc, 0,0,0);
    }
    __builtin_amdgcn_s_setprio(0);
    #pragma unroll
    for (int g=0; g<16; g++) dpart[g] += exp2f(acc[g] * SC2);
  }
  if (relhi >= clo){
    unsigned short* cur = Wa;
    unsigned short* prv = Wb;
    if (relhi < c_max){                        // boundary pre-build for chunk relhi+1
      const int dpr = l0w - 32*(relhi+1);
      const unsigned short* Erow = Ebf + (size_t)(dpr + lr)*64;
      f32x16 eacc = zero16();
      #pragma unroll
      for (int t=0;t<4;t++){
        bf16x8 ef = *(const bf16x8*)(Erow + t*16 + hi*8);
        eacc = __builtin_amdgcn_mfma_f32_32x32x16_bf16(qf[t], ef, eacc, 0,0,0);
      }
      #pragma unroll
      for (int g=0; g<16; g++) prv[ROWPAT(g,hi)*PSTR + lr] = f2bf(eacc[g]);
    }
    #pragma unroll 1
    for (int c = relhi; c >= clo; --c){
      const int s0 = c*32;
      const int delta = l0w - s0;
      {
        const unsigned short* Erow = Ebf + (size_t)(delta + lr)*64;
        f32x16 eacc = zero16();
        __builtin_amdgcn_s_setprio(1);
        #pragma unroll
        for (int t=0;t<4;t++){
          bf16x8 ef = *(const bf16x8*)(Erow + t*16 + hi*8);
          eacc = __builtin_amdgcn_mfma_f32_32x32x16_bf16(qf[t], ef, eacc, 0,0,0);
        }
        __builtin_amdgcn_s_setprio(0);
        #pragma unroll
        for (int g=0; g<16; g++) cur[ROWPAT(g,hi)*PSTR + lr] = f2bf(eacc[g]);
      }
      f32x16 acc = zero16();
      const unsigned short* Krow = Krows + (size_t)(s0 + lr)*64;
      __builtin_amdgcn_s_setprio(1);
      #pragma unroll
      for (int t=0;t<4;t++){
        bf16x8 kf = *(const bf16x8*)(Krow + t*16 + hi*8);
        acc = __builtin_amdgcn_mfma_f32_32x32x16_bf16(qf[t], kf, acc, 0,0,0);
      }
      __builtin_amdgcn_s_setprio(0);
      #pragma unroll
      for (int g=0; g<16; g++){
        const int rp = ROWPAT(g,hi);
        const int dloc = rp - lr;
        float v = acc[g];
        if (delta + dloc >= 0)
          v += bf2f(dloc >= 0 ? cur[rp*PSTR + dloc] : prv[rp*PSTR + 32 + dloc]);
        dpart[g] += exp2f(v * SC2);
      }
      unsigned short* tmp = cur; cur = prv; prv = tmp;
    }
  }
  // butterfly over 32 s-columns
  #pragma unroll
  for (int g=0; g<16; g++){
    float v = dpart[g];
    v += __shfl_xor(v, 1, 64);
    v += __shfl_xor(v, 2, 64);
    v += __shfl_xor(v, 4, 64);
    v += __shfl_xor(v, 8, 64);
    v += __shfl_xor(v, 16, 64);
    dpart[g] = v;
  }
  float* dtask = dws + (size_t)(bhg*64 + ltile)*128 + quarter*32;
  if (lr == 0){
    #pragma unroll
    for (int g=0; g<16; g++) dtask[ROWPAT(g,hi)] = dpart[g];
  }
}

// ---------------- K2b: attn_w + PV partial (8192 x 64 thr, recompute logits) ----------------
__global__ __launch_bounds__(64) void attn_pv_kernel(
    const unsigned short* __restrict__ Q,
    const unsigned short* __restrict__ Kb,
    const unsigned short* __restrict__ VT,   // chunk-blocked: [bh][c][dh][32]
    const unsigned short* __restrict__ Ebf,
    const float* __restrict__ dws,
    float* __restrict__ attn_w,
    float* __restrict__ po)
{
  __shared__ unsigned short slab[3*32*PSTR];   // Wa | Wb | Ps
  const int tid = threadIdx.x;
  const int lane = tid & 63;
  const int lr = lane & 31;
  const int hi = lane >> 5;
  ATTN_TASK_MAP();

  unsigned short* Wa = slab;
  unsigned short* Wb = Wa + 32*PSTR;
  unsigned short* Ps = Wb + 32*PSTR;

  const unsigned short* Qrow = Q + ((size_t)bhg*2048 + l0w + lr)*64;
  bf16x8 qf[4];
  #pragma unroll
  for (int t=0;t<4;t++) qf[t] = *(const bf16x8*)(Qrow + t*16 + hi*8);

  const unsigned short* Krows = Kb + (size_t)bhg*2048*64;
  const unsigned short* Vtb   = VT + (size_t)bhg*64*2048;

  const float* dtask = dws + (size_t)(bhg*64 + ltile)*128;
  float invd[16];
  #pragma unroll
  for (int g=0; g<16; g++){
    const int rp = ROWPAT(g,hi);
    invd[g] = 1.0f / (dtask[rp] + dtask[32 + rp] + dtask[64 + rp] + dtask[96 + rp]);
  }

  f32x16 oacc[2];
  oacc[0]=zero16(); oacc[1]=zero16();
  float* awbase = attn_w + ((size_t)bhg*2048 + l0w)*2048;

  #pragma unroll 1
  for (int c = nr_lo; c <= chi; ++c){          // no-rel chunks
    const int s0 = c*32;
    f32x16 acc = zero16();
    const unsigned short* Krow = Krows + (size_t)(s0 + lr)*64;
    __builtin_amdgcn_s_setprio(1);
    #pragma unroll
    for (int t=0;t<4;t++){
      bf16x8 kf = *(const bf16x8*)(Krow + t*16 + hi*8);
      acc = __builtin_amdgcn_mfma_f32_32x32x16_bf16(qf[t], kf, acc, 0,0,0);
    }
    __builtin_amdgcn_s_setprio(0);
    float p[16];
    #pragma unroll
    for (int g=0; g<16; g++){
      const int rp = ROWPAT(g,hi);
      p[g] = exp2f(acc[g] * SC2) * invd[g];
      __builtin_nontemporal_store(p[g], awbase + (size_t)rp*2048 + s0 + lr);
    }
    #pragma unroll
    for (int q=0;q<8;q++){
      const int rp0 = ROWPAT(2*q,hi);
      const unsigned pkv = pack2bf(p[2*q], p[2*q+1]);
      Ps[rp0*PSTR + lr]     = (unsigned short)(pkv & 0xFFFFu);
      Ps[(rp0+1)*PSTR + lr] = (unsigned short)(pkv >> 16);
    }
    bf16x8 af[2];
    #pragma unroll
    for (int sh=0; sh<2; sh++){
      const unsigned short* ap = Ps + lr*PSTR + sh*16 + 8*hi;
      u32x2 a0 = *(const u32x2*)(ap);
      u32x2 a1 = *(const u32x2*)(ap + 4);
      u32x4 w; w[0]=a0[0]; w[1]=a0[1]; w[2]=a1[0]; w[3]=a1[1];
      af[sh] = __builtin_bit_cast(bf16x8, w);
    }
    __builtin_amdgcn_s_setprio(1);
    #pragma unroll
    for (int sh=0; sh<2; sh++)
      #pragma unroll
      for (int dt=0; dt<2; dt++){
        bf16x8 vfr = *(const bf16x8*)(Vtb + (size_t)c*2048 + (size_t)(dt*32+lr)*32 + sh*16 + 8*hi);
        oacc[dt] = __builtin_amdgcn_mfma_f32_32x32x16_bf16(af[sh], vfr, oacc[dt], 0,0,0);
      }
    __builtin_amdgcn_s_setprio(0);
  }
  if (relhi >= clo){
    unsigned short* cur = Wa;
    unsigned short* prv = Wb;
    if (relhi < c_max){
      const int dpr = l0w - 32*(relhi+1);
      const unsigned short* Erow = Ebf + (size_t)(dpr + lr)*64;
      f32x16 eacc = zero16();
      #pragma unroll
      for (int t=0;t<4;t++){
        bf16x8 ef = *(const bf16x8*)(Erow + t*16 + hi*8);
        eacc = __builtin_amdgcn_mfma_f32_32x32x16_bf16(qf[t], ef, eacc, 0,0,0);
      }
      #pragma unroll
      for (int g=0; g<16; g++) prv[ROWPAT(g,hi)*PSTR + lr] = f2bf(eacc[g]);
    }
    #pragma unroll 1
    for (int c = relhi; c >= clo; --c){
      const int s0 = c*32;
      const int delta = l0w - s0;
      {
        const unsigned short* Erow = Ebf + (size_t)(delta + lr)*64;
        f32x16 eacc = zero16();
        __builtin_amdgcn_s_setprio(1);
        #pragma unroll
        for (int t=0;t<4;t++){
          bf16x8 ef = *(const bf16x8*)(Erow + t*16 + hi*8);
          eacc = __builtin_amdgcn_mfma_f32_32x32x16_bf16(qf[t], ef, eacc, 0,0,0);
        }
        __builtin_amdgcn_s_setprio(0);
        #pragma unroll
        for (int g=0; g<16; g++) cur[ROWPAT(g,hi)*PSTR + lr] = f2bf(eacc[g]);
      }
      f32x16 acc = zero16();
      const unsigned short* Krow = Krows + (size_t)(s0 + lr)*64;
      __builtin_amdgcn_s_setprio(1);
      #pragma unroll
      for (int t=0;t<4;t++){
        bf16x8 kf = *(const bf16x8*)(Krow + t*16 + hi*8);
        acc = __builtin_amdgcn_mfma_f32_32x32x16_bf16(qf[t], kf, acc, 0,0,0);
      }
      __builtin_amdgcn_s_setprio(0);
      float p[16];
      #pragma unroll
      for (int g=0; g<16; g++){
        const int rp = ROWPAT(g,hi);
        const int dloc = rp - lr;
        float v = acc[g];
        if (delta + dloc >= 0)
          v += bf2f(dloc >= 0 ? cur[rp*PSTR + dloc] : prv[rp*PSTR + 32 + dloc]);
        p[g] = exp2f(v * SC2) * invd[g];
        __builtin_nontemporal_store(p[g], awbase + (size_t)rp*2048 + s0 + lr);
      }
      #pragma unroll
      for (int q=0;q<8;q++){
        const int rp0 = ROWPAT(2*q,hi);
        const unsigned pkv = pack2bf(p[2*q], p[2*q+1]);
        Ps[rp0*PSTR + lr]     = (unsigned short)(pkv & 0xFFFFu);
        Ps[(rp0+1)*PSTR + lr] = (unsigned short)(pkv >> 16);
      }
      bf16x8 af[2];
      #pragma unroll
      for (int sh=0; sh<2; sh++){
        const unsigned short* ap = Ps + lr*PSTR + sh*16 + 8*hi;
        u32x2 a0 = *(const u32x2*)(ap);
        u32x2 a1 = *(const u32x2*)(ap + 4);
        u32x4 w; w[0]=a0[0]; w[1]=a0[1]; w[2]=a1[0]; w[3]=a1[1];
        af[sh] = __builtin_bit_cast(bf16x8, w);
      }
      __builtin_amdgcn_s_setprio(1);
      #pragma unroll
      for (int sh=0; sh<2; sh++)
        #pragma unroll
        for (int dt=0; dt<2; dt++){
          bf16x8 vfr = *(const bf16x8*)(Vtb + (size_t)c*2048 + (size_t)(dt*32+lr)*32 + sh*16 + 8*hi);
          oacc[dt] = __builtin_amdgcn_mfma_f32_32x32x16_bf16(af[sh], vfr, oacc[dt], 0,0,0);
        }
      __builtin_amdgcn_s_setprio(0);
      unsigned short* tmp = cur; cur = prv; prv = tmp;
    }
  }

  // store partial O (normalized, fp32) for this quarter
  float* pobase = po + (size_t)quarter*4194304 + ((size_t)bhg*2048 + l0w)*64;
  #pragma unroll
  for (int dt=0; dt<2; dt++)
    #pragma unroll
    for (int g=0; g<16; g++){
      const int rp = ROWPAT(g,hi);
      pobase[(size_t)rp*64 + dt*32 + lr] = oacc[dt][g];
    }
}

// ---------------- K2c: ATT = bf16(po0+po1+po2+po3) ----------------
__global__ __launch_bounds__(256) void pv_merge_kernel(const float* __restrict__ po,
                                                       unsigned short* __restrict__ ATT){
  const size_t i = ((size_t)blockIdx.x*256 + threadIdx.x)*8;
  f32x4 s0 = *(const f32x4*)(po + i);
  f32x4 s1 = *(const f32x4*)(po + i + 4);
  #pragma unroll
  for (int q=1; q<4; q++){
    s0 += *(const f32x4*)(po + (size_t)q*4194304 + i);
    s1 += *(const f32x4*)(po + (size_t)q*4194304 + i + 4);
  }
  u32x4 w;
  w[0] = pack2bf(s0[0], s0[1]);
  w[1] = pack2bf(s0[2], s0[3]);
  w[2] = pack2bf(s1[0], s1[1]);
  w[3] = pack2bf(s1[2], s1[3]);
  *(u32x4*)(ATT + i) = w;
}

// ---------------- K3: out(8192x512 fp32) = attn_gathered(bf16) @ fc_w + fc_b ----------------
__global__ __launch_bounds__(256,2) void fc_gemm_kernel(
    const unsigned short* __restrict__ A,
    const unsigned int* __restrict__ Wt,
    const float* __restrict__ bias, float* __restrict__ Out)
{
  __shared__ unsigned int Al[128][17];
  __shared__ unsigned int Bl[128][17];
  const int n0 = blockIdx.x * 128;
  const int m0 = blockIdx.y * 128;
  const int tid = threadIdx.x;
  const int lane = tid & 63, wave = tid >> 6;
  const int lr = lane & 31, hi = lane >> 5;
  const int wr = wave >> 1, wc = wave & 1;
  const int r = tid & 127, kh = tid >> 7;

  f32x16 acc[2][2];
  acc[0][0]=zero16(); acc[0][1]=zero16(); acc[1][0]=zero16(); acc[1][1]=zero16();

  for (int k0=0; k0<512; k0+=32){
    const int m = m0 + r; const int b = m >> 11, l = m & 2047;
    const int k = k0 + kh*16; const int h = k >> 6, dh0 = k & 63;
    const unsigned int* Ar = (const unsigned int*)(A + ((size_t)(b*8+h)*2048 + l)*64 + dh0);
    #pragma unroll
    for (int c=0;c<8;c++) Al[r][kh*8+c] = Ar[c];
    const unsigned int* Wr = Wt + (size_t)(n0 + r)*256 + (k0>>1) + kh*8;
    #pragma unroll
    for (int c=0;c<8;c++) Bl[r][kh*8 + c] = Wr[c];
    __syncthreads();
    #pragma unroll
    for (int t=0;t<2;t++){
      bf16x8 af[2], bfr[2];
      #pragma unroll
      for (int mt=0;mt<2;mt++){
        u32x4 w;
        #pragma unroll
        for (int j=0;j<4;j++) w[j] = Al[wr*64 + mt*32 + lr][t*8 + hi*4 + j];
        af[mt] = __builtin_bit_cast(bf16x8, w);
      }
      #pragma unroll
      for (int nt=0;nt<2;nt++){
        u32x4 w;
        #pragma unroll
        for (int j=0;j<4;j++) w[j] = Bl[wc*64 + nt*32 + lr][t*8 + hi*4 + j];
        bfr[nt] = __builtin_bit_cast(bf16x8, w);
      }
      #pragma unroll
      for (int mt=0;mt<2;mt++)
        #pragma unroll
        for (int nt=0;nt<2;nt++)
          acc[mt][nt] = __builtin_amdgcn_mfma_f32_32x32x16_bf16(af[mt], bfr[nt], acc[mt][nt], 0,0,0);
    }
    __syncthreads();
  }

  #pragma unroll
  for (int mt=0;mt<2;mt++)
    #pragma unroll
    for (int nt=0;nt<2;nt++){
      const int n = n0 + wc*64 + nt*32 + lr;
      const float bv = bias[n];
      #pragma unroll
      for (int g=0; g<16; g++){
        const int m2 = m0 + wr*64 + mt*32 + ROWPAT(g,hi);
        Out[(size_t)m2*512 + n] = acc[mt][nt][g] + bv;
      }
    }
}

extern "C" void kernel_launch(void* const* d_in, const int* in_sizes, int n_in,
                              void* d_out, int out_size, void* d_ws, size_t ws_size,
                              hipStream_t stream)
{
  const float* q_in = (const float*)d_in[0];
  const float* k_in = (const float*)d_in[1];
  const float* v_in = (const float*)d_in[2];
  const float* Wq_w = (const float*)d_in[3];
  const float* Wq_b = (const float*)d_in[4];
  const float* Wk_w = (const float*)d_in[5];
  const float* Wk_b = (const float*)d_in[6];
  const float* Wv_w = (const float*)d_in[7];
  const float* Wv_b = (const float*)d_in[8];
  const float* E    = (const float*)d_in[9];
  const float* fc_w = (const float*)d_in[10];
  const float* fc_b = (const float*)d_in[11];

  float* out = (float*)d_out;
  float* attn_w = out + (size_t)4*2048*512;

  unsigned short* Qws = (unsigned short*)d_ws;          // 4194304 elems each
  unsigned short* Kws = Qws + (size_t)4194304;
  unsigned short* VTs = Kws + (size_t)4194304;          // chunk-blocked V (written by proj3 z==2)
  unsigned short* ATT = VTs + (size_t)4194304;
  unsigned short* Ebf = ATT + (size_t)4194304;          // 131072 elems
  unsigned short* WqT = Ebf + 131072;
  unsigned short* WkT = WqT + 262144;
  unsigned short* WvT = WkT + 262144;
  unsigned short* WfT = WvT + 262144;
  float* po  = (float*)(WfT + 262144);                  // 4 x 4194304 fp32 (67 MB)
  float* dws = po + (size_t)4*4194304;                  // 4096 x 128 fp32 (2 MB)

  hipLaunchKernelGGL(transpose_w4_kernel, dim3(16,16,4), dim3(256), 0, stream,
                     Wq_w, Wk_w, Wv_w, fc_w, WqT, WkT, WvT, WfT);
  hipLaunchKernelGGL(erev_kernel, dim3(128), dim3(256), 0, stream, E, Ebf);

  hipLaunchKernelGGL(proj3_gemm_kernel, dim3(4,64,3), dim3(256), 0, stream,
                     q_in, k_in, v_in,
                     (const unsigned int*)WqT, (const unsigned int*)WkT, (const unsigned int*)WvT,
                     Wq_b, Wk_b, Wv_b, Qws, Kws, VTs);

  hipLaunchKernelGGL(attn_d_kernel,  dim3(8192), dim3(64), 0, stream, Qws, Kws, Ebf, dws);
  hipLaunchKernelGGL(attn_pv_kernel, dim3(8192), dim3(64), 0, stream, Qws, Kws, VTs, Ebf, dws, attn_w, po);
  hipLaunchKernelGGL(pv_merge_kernel, dim3(2048), dim3(256), 0, stream, po, ATT);

  hipLaunchKernelGGL(fc_gemm_kernel, dim3(4,64), dim3(256), 0, stream,
                     ATT, (const unsigned int*)WfT, fc_b, out);
}

// Round 20
// 403.999 us; speedup vs baseline: 1.0535x; 1.0535x over previous
//
#include <hip/hip_runtime.h>

#define SC2   0.18033688011112042f   // 0.125 * log2(e)
#define PSTR  36

typedef __attribute__((ext_vector_type(8)))  __bf16       bf16x8;
typedef __attribute__((ext_vector_type(16))) float        f32x16;
typedef __attribute__((ext_vector_type(4)))  float        f32x4;
typedef __attribute__((ext_vector_type(4)))  unsigned int u32x4;
typedef __attribute__((ext_vector_type(2)))  unsigned int u32x2;

#define ROWPAT(g, hi) ((((g)&3)) + 8*((g)>>2) + 4*(hi))

__device__ inline unsigned short f2bf(float f){
  unsigned u = __builtin_bit_cast(unsigned, f);
  u += 0x7FFFu + ((u >> 16) & 1u);
  return (unsigned short)(u >> 16);
}
__device__ inline float bf2f(unsigned short h){
  unsigned u = ((unsigned)h) << 16;
  return __builtin_bit_cast(float, u);
}
__device__ inline unsigned pack2bf(float lo, float hi){
  return (unsigned)f2bf(lo) | ((unsigned)f2bf(hi) << 16);
}
__device__ inline f32x16 zero16(){
  f32x16 z;
  #pragma unroll
  for (int i=0;i<16;i++) z[i]=0.f;
  return z;
}

// ---------------- K0: 4x W (512x512 fp32, [k][n]) -> Wt bf16 [n][k]; grid.z selects ----------------
__global__ __launch_bounds__(256) void transpose_w4_kernel(
    const float* __restrict__ Wq, const float* __restrict__ Wk,
    const float* __restrict__ Wv, const float* __restrict__ Wf,
    unsigned short* __restrict__ Tq, unsigned short* __restrict__ Tk,
    unsigned short* __restrict__ Tv, unsigned short* __restrict__ Tf){
  const int z = blockIdx.z;
  const float* W = z==0 ? Wq : (z==1 ? Wk : (z==2 ? Wv : Wf));
  unsigned short* Wt = z==0 ? Tq : (z==1 ? Tk : (z==2 ? Tv : Tf));
  __shared__ unsigned short t[32][33];
  const int n0 = blockIdx.x*32, k0 = blockIdx.y*32;
  const int tx = threadIdx.x & 31, ty = threadIdx.x >> 5;
  #pragma unroll
  for (int i=0;i<4;i++){
    int k = ty*4 + i;
    t[k][tx] = f2bf(W[(size_t)(k0+k)*512 + n0+tx]);
  }
  __syncthreads();
  #pragma unroll
  for (int i=0;i<4;i++){
    int n = ty*4+i;
    Wt[(size_t)(n0+n)*512 + k0 + tx] = t[tx][n];
  }
}

// ---------------- K0c: Ebf[u][d] = bf16(E[2047-u][d]) ----------------
__global__ __launch_bounds__(256) void erev_kernel(const float* __restrict__ E,
                                                   unsigned short* __restrict__ Ebf){
  const int i = blockIdx.x*256 + threadIdx.x;
  const int base = i*4;
  const int u = base >> 6, d = base & 63;
  f32x4 v = *(const f32x4*)(E + (size_t)(2047 - u)*64 + d);
  unsigned short o[4];
  #pragma unroll
  for (int j=0;j<4;j++) o[j] = f2bf(v[j]);
  *(u32x2*)(Ebf + (size_t)u*64 + d) = u32x2{(unsigned)o[0] | ((unsigned)o[1]<<16),
                                            (unsigned)o[2] | ((unsigned)o[3]<<16)};
}

// ---------------- K1: fused QKV projections; V (z==2) written chunk-blocked directly ----------------
__global__ __launch_bounds__(256,2) void proj3_gemm_kernel(
    const float* __restrict__ X0, const float* __restrict__ X1, const float* __restrict__ X2,
    const unsigned int* __restrict__ W0, const unsigned int* __restrict__ W1, const unsigned int* __restrict__ W2,
    const float* __restrict__ b0, const float* __restrict__ b1, const float* __restrict__ b2,
    unsigned short* __restrict__ Y0, unsigned short* __restrict__ Y1, unsigned short* __restrict__ Y2)
{
  const int z = blockIdx.z;
  const float* X = z==0 ? X0 : (z==1 ? X1 : X2);
  const unsigned int* Wt = z==0 ? W0 : (z==1 ? W1 : W2);
  const float* bias = z==0 ? b0 : (z==1 ? b1 : b2);
  unsigned short* Y = z==0 ? Y0 : (z==1 ? Y1 : Y2);

  __shared__ unsigned int Al[128][17];
  __shared__ unsigned int Bl[128][17];
  const int n0 = blockIdx.x * 128;
  const int m0 = blockIdx.y * 128;
  const int tid = threadIdx.x;
  const int lane = tid & 63, wave = tid >> 6;
  const int lr = lane & 31, hi = lane >> 5;
  const int wr = wave >> 1, wc = wave & 1;
  const int r = tid & 127, kh = tid >> 7;

  f32x16 acc[2][2];
  acc[0][0]=zero16(); acc[0][1]=zero16(); acc[1][0]=zero16(); acc[1][1]=zero16();

  for (int k0=0; k0<512; k0+=32){
    const float* Xr = X + (size_t)(m0 + r)*512 + k0 + kh*16;
    #pragma unroll
    for (int c=0;c<2;c++){
      f32x4 x0 = *(const f32x4*)(Xr + c*8);
      f32x4 x1 = *(const f32x4*)(Xr + c*8 + 4);
      Al[r][kh*8 + c*4 + 0] = pack2bf(x0[0], x0[1]);
      Al[r][kh*8 + c*4 + 1] = pack2bf(x0[2], x0[3]);
      Al[r][kh*8 + c*4 + 2] = pack2bf(x1[0], x1[1]);
      Al[r][kh*8 + c*4 + 3] = pack2bf(x1[2], x1[3]);
    }
    const unsigned int* Wr = Wt + (size_t)(n0 + r)*256 + (k0>>1) + kh*8;
    #pragma unroll
    for (int c=0;c<8;c++) Bl[r][kh*8 + c] = Wr[c];
    __syncthreads();
    #pragma unroll
    for (int t=0;t<2;t++){
      bf16x8 af[2], bfr[2];
      #pragma unroll
      for (int mt=0;mt<2;mt++){
        u32x4 w;
        #pragma unroll
        for (int j=0;j<4;j++) w[j] = Al[wr*64 + mt*32 + lr][t*8 + hi*4 + j];
        af[mt] = __builtin_bit_cast(bf16x8, w);
      }
      #pragma unroll
      for (int nt=0;nt<2;nt++){
        u32x4 w;
        #pragma unroll
        for (int j=0;j<4;j++) w[j] = Bl[wc*64 + nt*32 + lr][t*8 + hi*4 + j];
        bfr[nt] = __builtin_bit_cast(bf16x8, w);
      }
      #pragma unroll
      for (int mt=0;mt<2;mt++)
        #pragma unroll
        for (int nt=0;nt<2;nt++)
          acc[mt][nt] = __builtin_amdgcn_mfma_f32_32x32x16_bf16(af[mt], bfr[nt], acc[mt][nt], 0,0,0);
    }
    __syncthreads();
  }

  #pragma unroll
  for (int mt=0;mt<2;mt++)
    #pragma unroll
    for (int nt=0;nt<2;nt++){
      const int n = n0 + wc*64 + nt*32 + lr;
      const float bv = bias[n];
      const int h = n >> 6, dh = n & 63;
      #pragma unroll
      for (int g=0; g<16; g++){
        const int m = m0 + wr*64 + mt*32 + ROWPAT(g,hi);
        const int b = m >> 11, l = m & 2047;
        const unsigned short val = f2bf(acc[mt][nt][g] + bv);
        if (z == 2){
          // chunk-blocked V: [bh][l>>5][dh][l&31]
          Y[(size_t)(b*8 + h)*131072 + (size_t)(l >> 5)*2048 + (size_t)dh*32 + (l & 31)] = val;
        } else {
          Y[((size_t)(b*8 + h)*2048 + l)*64 + dh] = val;
        }
      }
    }
}

// ---- task mapping shared by K2a/K2b: bid in [0,8192); quarter s-ranges ----
#define ATTN_TASK_MAP()                                   \
  const int bid = blockIdx.x;                             \
  const int xcd = bid & 7;                                \
  const int j   = bid >> 3;      /* 0..1023 */            \
  const int bhg = xcd*4 + (j >> 8);                       \
  const int jj  = j & 255;                                \
  const int quarter = jj & 3;                             \
  const int ltile = 63 - (jj >> 2);                       \
  const int l0w = ltile*32;                               \
  const int c_max = ltile;                                \
  const int clo = quarter*16, chi = clo + 15;             \
  const int relhi = c_max < chi ? c_max : chi;            \
  const int nr_lo = (c_max+1 > clo) ? c_max+1 : clo;

// ---------------- K2a: denominator pass (8192 x 64 thr, zero barriers) ----------------
__global__ __launch_bounds__(64) void attn_d_kernel(
    const unsigned short* __restrict__ Q,
    const unsigned short* __restrict__ Kb,
    const unsigned short* __restrict__ Ebf,
    float* __restrict__ dws)
{
  __shared__ unsigned short slab[2*32*PSTR];   // Wa | Wb
  const int tid = threadIdx.x;
  const int lane = tid & 63;
  const int lr = lane & 31;
  const int hi = lane >> 5;
  ATTN_TASK_MAP();

  unsigned short* Wa = slab;
  unsigned short* Wb = Wa + 32*PSTR;

  const unsigned short* Qrow = Q + ((size_t)bhg*2048 + l0w + lr)*64;
  bf16x8 qf[4];
  #pragma unroll
  for (int t=0;t<4;t++) qf[t] = *(const bf16x8*)(Qrow + t*16 + hi*8);
  const unsigned short* Krows = Kb + (size_t)bhg*2048*64;

  float dpart[16];
  #pragma unroll
  for (int g=0;g<16;g++) dpart[g] = 0.f;

  #pragma unroll 2
  for (int c = nr_lo; c <= chi; ++c){          // no-rel chunks
    const int s0 = c*32;
    f32x16 acc = zero16();
    const unsigned short* Krow = Krows + (size_t)(s0 + lr)*64;
    #pragma unroll
    for (int t=0;t<4;t++){
      bf16x8 kf = *(const bf16x8*)(Krow + t*16 + hi*8);
      acc = __builtin_amdgcn_mfma_f32_32x32x16_bf16(qf[t], kf, acc, 0,0,0);
    }
    #pragma unroll
    for (int g=0; g<16; g++) dpart[g] += exp2f(acc[g] * SC2);
  }
  if (relhi >= clo){
    unsigned short* cur = Wa;
    unsigned short* prv = Wb;
    if (relhi < c_max){                        // boundary pre-build for chunk relhi+1
      const int dpr = l0w - 32*(relhi+1);
      const unsigned short* Erow = Ebf + (size_t)(dpr + lr)*64;
      f32x16 eacc = zero16();
      #pragma unroll
      for (int t=0;t<4;t++){
        bf16x8 ef = *(const bf16x8*)(Erow + t*16 + hi*8);
        eacc = __builtin_amdgcn_mfma_f32_32x32x16_bf16(qf[t], ef, eacc, 0,0,0);
      }
      #pragma unroll
      for (int g=0; g<16; g++) prv[ROWPAT(g,hi)*PSTR + lr] = f2bf(eacc[g]);
    }
    #pragma unroll 1
    for (int c = relhi; c >= clo; --c){
      const int s0 = c*32;
      const int delta = l0w - s0;
      {
        const unsigned short* Erow = Ebf + (size_t)(delta + lr)*64;
        f32x16 eacc = zero16();
        #pragma unroll
        for (int t=0;t<4;t++){
          bf16x8 ef = *(const bf16x8*)(Erow + t*16 + hi*8);
          eacc = __builtin_amdgcn_mfma_f32_32x32x16_bf16(qf[t], ef, eacc, 0,0,0);
        }
        #pragma unroll
        for (int g=0; g<16; g++) cur[ROWPAT(g,hi)*PSTR + lr] = f2bf(eacc[g]);
      }
      f32x16 acc = zero16();
      const unsigned short* Krow = Krows + (size_t)(s0 + lr)*64;
      #pragma unroll
      for (int t=0;t<4;t++){
        bf16x8 kf = *(const bf16x8*)(Krow + t*16 + hi*8);
        acc = __builtin_amdgcn_mfma_f32_32x32x16_bf16(qf[t], kf, acc, 0,0,0);
      }
      #pragma unroll
      for (int g=0; g<16; g++){
        const int rp = ROWPAT(g,hi);
        const int dloc = rp - lr;
        float v = acc[g];
        if (delta + dloc >= 0)
          v += bf2f(dloc >= 0 ? cur[rp*PSTR + dloc] : prv[rp*PSTR + 32 + dloc]);
        dpart[g] += exp2f(v * SC2);
      }
      unsigned short* tmp = cur; cur = prv; prv = tmp;
    }
  }
  // butterfly over 32 s-columns
  #pragma unroll
  for (int g=0; g<16; g++){
    float v = dpart[g];
    v += __shfl_xor(v, 1, 64);
    v += __shfl_xor(v, 2, 64);
    v += __shfl_xor(v, 4, 64);
    v += __shfl_xor(v, 8, 64);
    v += __shfl_xor(v, 16, 64);
    dpart[g] = v;
  }
  float* dtask = dws + (size_t)(bhg*64 + ltile)*128 + quarter*32;
  if (lr == 0){
    #pragma unroll
    for (int g=0; g<16; g++) dtask[ROWPAT(g,hi)] = dpart[g];
  }
}

// ---------------- K2b: attn_w + PV partial (8192 x 64 thr, recompute logits) ----------------
__global__ __launch_bounds__(64) void attn_pv_kernel(
    const unsigned short* __restrict__ Q,
    const unsigned short* __restrict__ Kb,
    const unsigned short* __restrict__ VT,   // chunk-blocked: [bh][c][dh][32]
    const unsigned short* __restrict__ Ebf,
    const float* __restrict__ dws,
    float* __restrict__ attn_w,
    float* __restrict__ po)
{
  __shared__ unsigned short slab[3*32*PSTR];   // Wa | Wb | Ps
  const int tid = threadIdx.x;
  const int lane = tid & 63;
  const int lr = lane & 31;
  const int hi = lane >> 5;
  ATTN_TASK_MAP();

  unsigned short* Wa = slab;
  unsigned short* Wb = Wa + 32*PSTR;
  unsigned short* Ps = Wb + 32*PSTR;

  const unsigned short* Qrow = Q + ((size_t)bhg*2048 + l0w + lr)*64;
  bf16x8 qf[4];
  #pragma unroll
  for (int t=0;t<4;t++) qf[t] = *(const bf16x8*)(Qrow + t*16 + hi*8);

  const unsigned short* Krows = Kb + (size_t)bhg*2048*64;
  const unsigned short* Vtb   = VT + (size_t)bhg*64*2048;

  const float* dtask = dws + (size_t)(bhg*64 + ltile)*128;
  float invd[16];
  #pragma unroll
  for (int g=0; g<16; g++){
    const int rp = ROWPAT(g,hi);
    invd[g] = 1.0f / (dtask[rp] + dtask[32 + rp] + dtask[64 + rp] + dtask[96 + rp]);
  }

  f32x16 oacc[2];
  oacc[0]=zero16(); oacc[1]=zero16();
  float* awbase = attn_w + ((size_t)bhg*2048 + l0w)*2048;

  #pragma unroll 1
  for (int c = nr_lo; c <= chi; ++c){          // no-rel chunks
    const int s0 = c*32;
    f32x16 acc = zero16();
    const unsigned short* Krow = Krows + (size_t)(s0 + lr)*64;
    #pragma unroll
    for (int t=0;t<4;t++){
      bf16x8 kf = *(const bf16x8*)(Krow + t*16 + hi*8);
      acc = __builtin_amdgcn_mfma_f32_32x32x16_bf16(qf[t], kf, acc, 0,0,0);
    }
    float p[16];
    #pragma unroll
    for (int g=0; g<16; g++){
      const int rp = ROWPAT(g,hi);
      p[g] = exp2f(acc[g] * SC2) * invd[g];
      __builtin_nontemporal_store(p[g], awbase + (size_t)rp*2048 + s0 + lr);
    }
    #pragma unroll
    for (int q=0;q<8;q++){
      const int rp0 = ROWPAT(2*q,hi);
      const unsigned pkv = pack2bf(p[2*q], p[2*q+1]);
      Ps[rp0*PSTR + lr]     = (unsigned short)(pkv & 0xFFFFu);
      Ps[(rp0+1)*PSTR + lr] = (unsigned short)(pkv >> 16);
    }
    bf16x8 af[2];
    #pragma unroll
    for (int sh=0; sh<2; sh++){
      const unsigned short* ap = Ps + lr*PSTR + sh*16 + 8*hi;
      u32x2 a0 = *(const u32x2*)(ap);
      u32x2 a1 = *(const u32x2*)(ap + 4);
      u32x4 w; w[0]=a0[0]; w[1]=a0[1]; w[2]=a1[0]; w[3]=a1[1];
      af[sh] = __builtin_bit_cast(bf16x8, w);
    }
    #pragma unroll
    for (int sh=0; sh<2; sh++)
      #pragma unroll
      for (int dt=0; dt<2; dt++){
        bf16x8 vfr = *(const bf16x8*)(Vtb + (size_t)c*2048 + (size_t)(dt*32+lr)*32 + sh*16 + 8*hi);
        oacc[dt] = __builtin_amdgcn_mfma_f32_32x32x16_bf16(af[sh], vfr, oacc[dt], 0,0,0);
      }
  }
  if (relhi >= clo){
    unsigned short* cur = Wa;
    unsigned short* prv = Wb;
    if (relhi < c_max){
      const int dpr = l0w - 32*(relhi+1);
      const unsigned short* Erow = Ebf + (size_t)(dpr + lr)*64;
      f32x16 eacc = zero16();
      #pragma unroll
      for (int t=0;t<4;t++){
        bf16x8 ef = *(const bf16x8*)(Erow + t*16 + hi*8);
        eacc = __builtin_amdgcn_mfma_f32_32x32x16_bf16(qf[t], ef, eacc, 0,0,0);
      }
      #pragma unroll
      for (int g=0; g<16; g++) prv[ROWPAT(g,hi)*PSTR + lr] = f2bf(eacc[g]);
    }
    #pragma unroll 1
    for (int c = relhi; c >= clo; --c){
      const int s0 = c*32;
      const int delta = l0w - s0;
      {
        const unsigned short* Erow = Ebf + (size_t)(delta + lr)*64;
        f32x16 eacc = zero16();
        #pragma unroll
        for (int t=0;t<4;t++){
          bf16x8 ef = *(const bf16x8*)(Erow + t*16 + hi*8);
          eacc = __builtin_amdgcn_mfma_f32_32x32x16_bf16(qf[t], ef, eacc, 0,0,0);
        }
        #pragma unroll
        for (int g=0; g<16; g++) cur[ROWPAT(g,hi)*PSTR + lr] = f2bf(eacc[g]);
      }
      f32x16 acc = zero16();
      const unsigned short* Krow = Krows + (size_t)(s0 + lr)*64;
      #pragma unroll
      for (int t=0;t<4;t++){
        bf16x8 kf = *(const bf16x8*)(Krow + t*16 + hi*8);
        acc = __builtin_amdgcn_mfma_f32_32x32x16_bf16(qf[t], kf, acc, 0,0,0);
      }
      float p[16];
      #pragma unroll
      for (int g=0; g<16; g++){
        const int rp = ROWPAT(g,hi);
        const int dloc = rp - lr;
        float v = acc[g];
        if (delta + dloc >= 0)
          v += bf2f(dloc >= 0 ? cur[rp*PSTR + dloc] : prv[rp*PSTR + 32 + dloc]);
        p[g] = exp2f(v * SC2) * invd[g];
        __builtin_nontemporal_store(p[g], awbase + (size_t)rp*2048 + s0 + lr);
      }
      #pragma unroll
      for (int q=0;q<8;q++){
        const int rp0 = ROWPAT(2*q,hi);
        const unsigned pkv = pack2bf(p[2*q], p[2*q+1]);
        Ps[rp0*PSTR + lr]     = (unsigned short)(pkv & 0xFFFFu);
        Ps[(rp0+1)*PSTR + lr] = (unsigned short)(pkv >> 16);
      }
      bf16x8 af[2];
      #pragma unroll
      for (int sh=0; sh<2; sh++){
        const unsigned short* ap = Ps + lr*PSTR + sh*16 + 8*hi;
        u32x2 a0 = *(const u32x2*)(ap);
        u32x2 a1 = *(const u32x2*)(ap + 4);
        u32x4 w; w[0]=a0[0]; w[1]=a0[1]; w[2]=a1[0]; w[3]=a1[1];
        af[sh] = __builtin_bit_cast(bf16x8, w);
      }
      #pragma unroll
      for (int sh=0; sh<2; sh++)
        #pragma unroll
        for (int dt=0; dt<2; dt++){
          bf16x8 vfr = *(const bf16x8*)(Vtb + (size_t)c*2048 + (size_t)(dt*32+lr)*32 + sh*16 + 8*hi);
          oacc[dt] = __builtin_amdgcn_mfma_f32_32x32x16_bf16(af[sh], vfr, oacc[dt], 0,0,0);
        }
      unsigned short* tmp = cur; cur = prv; prv = tmp;
    }
  }

  // store partial O (normalized, fp32) for this quarter
  float* pobase = po + (size_t)quarter*4194304 + ((size_t)bhg*2048 + l0w)*64;
  #pragma unroll
  for (int dt=0; dt<2; dt++)
    #pragma unroll
    for (int g=0; g<16; g++){
      const int rp = ROWPAT(g,hi);
      pobase[(size_t)rp*64 + dt*32 + lr] = oacc[dt][g];
    }
}

// ---------------- K2c: ATT = bf16(po0+po1+po2+po3) ----------------
__global__ __launch_bounds__(256) void pv_merge_kernel(const float* __restrict__ po,
                                                       unsigned short* __restrict__ ATT){
  const size_t i = ((size_t)blockIdx.x*256 + threadIdx.x)*8;
  f32x4 s0 = *(const f32x4*)(po + i);
  f32x4 s1 = *(const f32x4*)(po + i + 4);
  #pragma unroll
  for (int q=1; q<4; q++){
    s0 += *(const f32x4*)(po + (size_t)q*4194304 + i);
    s1 += *(const f32x4*)(po + (size_t)q*4194304 + i + 4);
  }
  u32x4 w;
  w[0] = pack2bf(s0[0], s0[1]);
  w[1] = pack2bf(s0[2], s0[3]);
  w[2] = pack2bf(s1[0], s1[1]);
  w[3] = pack2bf(s1[2], s1[3]);
  *(u32x4*)(ATT + i) = w;
}

// ---------------- K3: out(8192x512 fp32) = attn_gathered(bf16) @ fc_w + fc_b ----------------
__global__ __launch_bounds__(256,2) void fc_gemm_kernel(
    const unsigned short* __restrict__ A,
    const unsigned int* __restrict__ Wt,
    const float* __restrict__ bias, float* __restrict__ Out)
{
  __shared__ unsigned int Al[128][17];
  __shared__ unsigned int Bl[128][17];
  const int n0 = blockIdx.x * 128;
  const int m0 = blockIdx.y * 128;
  const int tid = threadIdx.x;
  const int lane = tid & 63, wave = tid >> 6;
  const int lr = lane & 31, hi = lane >> 5;
  const int wr = wave >> 1, wc = wave & 1;
  const int r = tid & 127, kh = tid >> 7;

  f32x16 acc[2][2];
  acc[0][0]=zero16(); acc[0][1]=zero16(); acc[1][0]=zero16(); acc[1][1]=zero16();

  for (int k0=0; k0<512; k0+=32){
    const int m = m0 + r; const int b = m >> 11, l = m & 2047;
    const int k = k0 + kh*16; const int h = k >> 6, dh0 = k & 63;
    const unsigned int* Ar = (const unsigned int*)(A + ((size_t)(b*8+h)*2048 + l)*64 + dh0);
    #pragma unroll
    for (int c=0;c<8;c++) Al[r][kh*8+c] = Ar[c];
    const unsigned int* Wr = Wt + (size_t)(n0 + r)*256 + (k0>>1) + kh*8;
    #pragma unroll
    for (int c=0;c<8;c++) Bl[r][kh*8 + c] = Wr[c];
    __syncthreads();
    #pragma unroll
    for (int t=0;t<2;t++){
      bf16x8 af[2], bfr[2];
      #pragma unroll
      for (int mt=0;mt<2;mt++){
        u32x4 w;
        #pragma unroll
        for (int j=0;j<4;j++) w[j] = Al[wr*64 + mt*32 + lr][t*8 + hi*4 + j];
        af[mt] = __builtin_bit_cast(bf16x8, w);
      }
      #pragma unroll
      for (int nt=0;nt<2;nt++){
        u32x4 w;
        #pragma unroll
        for (int j=0;j<4;j++) w[j] = Bl[wc*64 + nt*32 + lr][t*8 + hi*4 + j];
        bfr[nt] = __builtin_bit_cast(bf16x8, w);
      }
      #pragma unroll
      for (int mt=0;mt<2;mt++)
        #pragma unroll
        for (int nt=0;nt<2;nt++)
          acc[mt][nt] = __builtin_amdgcn_mfma_f32_32x32x16_bf16(af[mt], bfr[nt], acc[mt][nt], 0,0,0);
    }
    __syncthreads();
  }

  #pragma unroll
  for (int mt=0;mt<2;mt++)
    #pragma unroll
    for (int nt=0;nt<2;nt++){
      const int n = n0 + wc*64 + nt*32 + lr;
      const float bv = bias[n];
      #pragma unroll
      for (int g=0; g<16; g++){
        const int m2 = m0 + wr*64 + mt*32 + ROWPAT(g,hi);
        Out[(size_t)m2*512 + n] = acc[mt][nt][g] + bv;
      }
    }
}

extern "C" void kernel_launch(void* const* d_in, const int* in_sizes, int n_in,
                              void* d_out, int out_size, void* d_ws, size_t ws_size,
                              hipStream_t stream)
{
  const float* q_in = (const float*)d_in[0];
  const float* k_in = (const float*)d_in[1];
  const float* v_in = (const float*)d_in[2];
  const float* Wq_w = (const float*)d_in[3];
  const float* Wq_b = (const float*)d_in[4];
  const float* Wk_w = (const float*)d_in[5];
  const float* Wk_b = (const float*)d_in[6];
  const float* Wv_w = (const float*)d_in[7];
  const float* Wv_b = (const float*)d_in[8];
  const float* E    = (const float*)d_in[9];
  const float* fc_w = (const float*)d_in[10];
  const float* fc_b = (const float*)d_in[11];

  float* out = (float*)d_out;
  float* attn_w = out + (size_t)4*2048*512;

  unsigned short* Qws = (unsigned short*)d_ws;          // 4194304 elems each
  unsigned short* Kws = Qws + (size_t)4194304;
  unsigned short* VTs = Kws + (size_t)4194304;          // chunk-blocked V (written by proj3 z==2)
  unsigned short* ATT = VTs + (size_t)4194304;
  unsigned short* Ebf = ATT + (size_t)4194304;          // 131072 elems
  unsigned short* WqT = Ebf + 131072;
  unsigned short* WkT = WqT + 262144;
  unsigned short* WvT = WkT + 262144;
  unsigned short* WfT = WvT + 262144;
  float* po  = (float*)(WfT + 262144);                  // 4 x 4194304 fp32 (67 MB)
  float* dws = po + (size_t)4*4194304;                  // 4096 x 128 fp32 (2 MB)

  hipLaunchKernelGGL(transpose_w4_kernel, dim3(16,16,4), dim3(256), 0, stream,
                     Wq_w, Wk_w, Wv_w, fc_w, WqT, WkT, WvT, WfT);
  hipLaunchKernelGGL(erev_kernel, dim3(128), dim3(256), 0, stream, E, Ebf);

  hipLaunchKernelGGL(proj3_gemm_kernel, dim3(4,64,3), dim3(256), 0, stream,
                     q_in, k_in, v_in,
                     (const unsigned int*)WqT, (const unsigned int*)WkT, (const unsigned int*)WvT,
                     Wq_b, Wk_b, Wv_b, Qws, Kws, VTs);

  hipLaunchKernelGGL(attn_d_kernel,  dim3(8192), dim3(64), 0, stream, Qws, Kws, Ebf, dws);
  hipLaunchKernelGGL(attn_pv_kernel, dim3(8192), dim3(64), 0, stream, Qws, Kws, VTs, Ebf, dws, attn_w, po);
  hipLaunchKernelGGL(pv_merge_kernel, dim3(2048), dim3(256), 0, stream, po, ATT);

  hipLaunchKernelGGL(fc_gemm_kernel, dim3(4,64), dim3(256), 0, stream,
                     ATT, (const unsigned int*)WfT, fc_b, out);
}